// Round 11
// baseline (968.815 us; speedup 1.0000x reference)
//
#include <hip/hip_runtime.h>
#include <hip/hip_bf16.h>
#include <stdint.h>

#define Rdim 1023
#define BFR  4190208           // 64*64*1023

typedef __bf16 bf16;
typedef __bf16 bf16x8 __attribute__((ext_vector_type(8)));
typedef __bf16 bf16x4 __attribute__((ext_vector_type(4)));
typedef float  f32x4  __attribute__((ext_vector_type(4)));
typedef float  f32x4u __attribute__((ext_vector_type(4), aligned(4)));

__device__ __forceinline__ void async16(const void* g, void* l) {
    __builtin_amdgcn_global_load_lds(
        (const __attribute__((address_space(1))) void*)g,
        (__attribute__((address_space(3))) void*)l, 16, 0, 0);
}

#define BAR()  do { __builtin_amdgcn_s_barrier(); __builtin_amdgcn_sched_barrier(0); } while(0)

// ---------------------------------------------------------------------------
// Producer helpers — r10's proven prep bodies (2-bit/64B-window swizzle for
// BK=32: chunk c of row m stored at (c&~3)|((c&3)^((m>>1)&3))).
// ---------------------------------------------------------------------------
__device__ __forceinline__ void prep_args_row(
    int m, int t, const float* __restrict__ x,
    const float* __restrict__ w0, const float* __restrict__ w1,
    const float* __restrict__ w2, const float* __restrict__ w3,
    bf16* __restrict__ args)
{
    const int b = m >> 6;
    float wr0[16], wr1[16], wr2[16], wr3[16];
#pragma unroll
    for (int l = 0; l < 16; ++l) {
        wr0[l] = w0[b*16 + l]; wr1[l] = w1[b*16 + l];
        wr2[l] = w2[b*16 + l]; wr3[l] = w3[b*16 + l];
    }
    const float* xb = x + ((size_t)(b*16)*64 + (m & 63)) * (size_t)Rdim;
    float a0[4] = {}, a1[4] = {}, a2[4] = {}, a3[4] = {};
    if (t < 255) {
#pragma unroll
        for (int l = 0; l < 16; ++l) {
            f32x4u v = *(const f32x4u*)(xb + (size_t)l*(64*(size_t)Rdim) + t*4);
#pragma unroll
            for (int j = 0; j < 4; ++j) {
                a0[j] += wr0[l]*v[j]; a1[j] += wr1[l]*v[j];
                a2[j] += wr2[l]*v[j]; a3[j] += wr3[l]*v[j];
            }
        }
    } else {
#pragma unroll
        for (int l = 0; l < 16; ++l) {
            const float* p = xb + (size_t)l*(64*(size_t)Rdim) + 1020;
#pragma unroll
            for (int j = 0; j < 3; ++j) {
                float v = p[j];
                a0[j] += wr0[l]*v; a1[j] += wr1[l]*v;
                a2[j] += wr2[l]*v; a3[j] += wr3[l]*v;
            }
        }
    }
    const int c   = t >> 1;
    const int S2  = (m >> 1) & 3;
    const int cw  = (c & ~3) | ((c & 3) ^ S2);
    const int off = (cw << 3) + ((t & 1) << 2);
    bf16x4 s0, s1, s2, s3;
#pragma unroll
    for (int j = 0; j < 4; ++j) {
        s0[j] = (bf16)a0[j]; s1[j] = (bf16)a1[j];
        s2[j] = (bf16)a2[j]; s3[j] = (bf16)a3[j];
    }
    *(bf16x4*)(args +            (size_t)m*1024 + off) = s0;   // car
    *(bf16x4*)(args + 4194304 +  (size_t)m*1024 + off) = s1;   // cdr
    bf16* c12 = args + 8388608 + (size_t)m*2048;
    *(bf16x4*)(c12 + off)        = s2;                         // c1
    *(bf16x4*)(c12 + 1024 + off) = s3;                         // c2
}

__device__ __forceinline__ void prep_dpad_chunk(
    int id, const float* __restrict__ Dl, const float* __restrict__ Dr,
    const float* __restrict__ El, const float* __restrict__ Er,
    bf16* __restrict__ dpad)
{
    const float* src; int n, c, K; size_t base;
    if (id < 262144) {
        const int m2  = id >> 17;
        src = m2 ? Dr : Dl;
        const int rem = id & 131071;
        n = rem >> 7; c = rem & 127; K = 1024;
        base = m2 ? 1048576u : 0u;
    } else {
        const int rem = id - 262144;
        n = rem >> 8; c = rem & 255; K = 2048;
        base = 2097152u;
        src = (c < 128) ? El : Er;
    }
    const int cl = c & 127;
    float v[8] = {};
    if (n < Rdim) {
        const float* sp = src + (size_t)n*Rdim + cl*8;
        if (cl < 127) {
            f32x4u u0 = *(const f32x4u*)sp;
            f32x4u u1 = *(const f32x4u*)(sp + 4);
#pragma unroll
            for (int j = 0; j < 4; ++j) { v[j] = u0[j]; v[4+j] = u1[j]; }
        } else {
            f32x4u u0 = *(const f32x4u*)sp;
#pragma unroll
            for (int j = 0; j < 4; ++j) v[j] = u0[j];
            v[4] = sp[4]; v[5] = sp[5]; v[6] = sp[6];
        }
    }
    const int swc = (c & ~3) | ((c & 3) ^ ((n >> 1) & 3));
    bf16x8 s;
#pragma unroll
    for (int j = 0; j < 8; ++j) s[j] = (bf16)v[j];
    *(bf16x8*)(dpad + base + (size_t)n*K + swc*8) = s;
}

__device__ __forceinline__ void prep_stats(
    int t, const float* __restrict__ w0, const float* __restrict__ w1,
    const float* __restrict__ w2, const float* __restrict__ w3,
    float* __restrict__ out)
{
    const int k = t >> 6, b2 = t & 63;
    const float* w = (k==0) ? w0 : (k==1) ? w1 : (k==2) ? w2 : w3;
    float s = 0.f, mx = -1e30f;
#pragma unroll
    for (int l = 0; l < 16; ++l) {
        float p = w[b2*16 + l];
        s += p * logf(p + 1e-12f);
        mx = fmaxf(mx, p);
    }
    out[3*(size_t)BFR +       k*64 + b2] = -s / logf(16.f);
    out[3*(size_t)BFR + 256 + k*64 + b2] = mx;
}

// ---------------------------------------------------------------------------
// GEMM tile — r10's proven BK=32 1-barrier pipeline, BM=128, B region
// rebased to 24576 (LDS total 72 KiB -> 2 blocks/CU).
// ---------------------------------------------------------------------------
template<int NKT, bool CONS>
__device__ __forceinline__ void gemm_t(
    const bf16* __restrict__ Ab, const bf16* __restrict__ Bb,
    const float* __restrict__ rf, const float* __restrict__ rr,
    float* __restrict__ outp, char* lds, int mt, int nt)
{
    constexpr int AstB = CONS ? 4096 : 2048;   // row stride bytes (A and B)

    const int tid  = threadIdx.x;
    const int wave = tid >> 6, lane = tid & 63;
    const int wm   = wave >> 2, wn = wave & 3; // 2M x 4N
    const int lr   = lane & 15, lk = lane >> 4;
    const int cc16 = (lk ^ ((lr >> 1) & 3)) << 4;

    const char* AgT = (const char*)Ab + (size_t)(mt*128 + (tid>>2))*AstB + (tid&3)*16;
    const char* BgT = (const char*)Bb + (size_t)(nt*256 + (tid>>2))*AstB + (tid&3)*16;

    f32x4 acc[4][4] = {};
    bf16x8 af[4], bfr[4];

#define STG(bufidx, kt) do {                                                  \
    char* _a = lds + (bufidx)*8192  + wave*1024;                              \
    char* _b = lds + 24576 + (bufidx)*16384 + wave*1024;                      \
    const size_t _ko = (size_t)(kt)*64;                                       \
    async16(AgT + _ko, _a);                                                   \
    async16(BgT + _ko, _b);                                                   \
    async16(BgT + (size_t)128*AstB + _ko, _b + 8192);                         \
} while(0)

    STG(0, 0); STG(1, 1);
    asm volatile("s_waitcnt vmcnt(3)" ::: "memory");
    BAR();

    int cb = 0;
    for (int kt = 0; kt < NKT; ++kt) {
        char* cA = lds + cb*8192;
        char* cB = lds + 24576 + cb*16384;
        int sb = cb + 2; if (sb >= 3) sb -= 3;
        const bool st = (kt + 2 < NKT);
#pragma unroll
        for (int mi = 0; mi < 4; ++mi)
            af[mi] = *(const bf16x8*)(cA + (wm*64 + mi*16 + lr)*64 + cc16);
#pragma unroll
        for (int j = 0; j < 4; ++j)
            bfr[j] = *(const bf16x8*)(cB + (wn*64 + j*16 + lr)*64 + cc16);
        if (st) STG(sb, kt+2);
        __builtin_amdgcn_s_setprio(1);
#pragma unroll
        for (int mi = 0; mi < 4; ++mi)
#pragma unroll
        for (int j = 0; j < 4; ++j)
            acc[mi][j] = __builtin_amdgcn_mfma_f32_16x16x32_bf16(
                af[mi], bfr[j], acc[mi][j], 0, 0, 0);
        __builtin_amdgcn_s_setprio(0);
        if (st)                { asm volatile("s_waitcnt vmcnt(3)" ::: "memory"); }
        else if (kt == NKT-2)  { asm volatile("s_waitcnt vmcnt(0)" ::: "memory"); }
        BAR();
        cb = cb + 1; if (cb == 3) cb = 0;
    }
#undef STG

#pragma unroll
    for (int mi = 0; mi < 4; ++mi) {
        const int gm0 = mt*128 + wm*64 + mi*16 + lk*4;
#pragma unroll
        for (int j = 0; j < 4; ++j) {
            const int gn = nt*256 + wn*64 + j*16 + lr;
            if (gn < Rdim) {
                const float rv = CONS ? rr[gn] : 0.f;
#pragma unroll
                for (int q = 0; q < 4; ++q) {
                    float v = acc[mi][j][q];
                    if (CONS) v += rf[gm0 + q] * rv;
                    outp[(size_t)(gm0 + q)*Rdim + gn] = v;
                }
            }
        }
    }
}

// ---------------------------------------------------------------------------
// Fused overlap kernel: 384 blocks x 512 thr, 72 KiB -> 2 blocks/CU, all
// co-resident. bid<128: producer (dpad -> flag0; 16 args batches -> flag1+g;
// stats) then joins consumption. Consumers: relaxed-poll (s_sleep, NO
// acquire in the loop — the r8 lesson), ONE acquire fence per new batch.
// 384 tiles in 16 batches x 24 (8 cons + 8 car + 8 cdr, cons first).
// ---------------------------------------------------------------------------
__global__ __launch_bounds__(512, 2) void k_all(
    const float* __restrict__ x,
    const float* __restrict__ w0, const float* __restrict__ w1,
    const float* __restrict__ w2, const float* __restrict__ w3,
    const float* __restrict__ Dl, const float* __restrict__ Dr,
    const float* __restrict__ El, const float* __restrict__ Er,
    const float* __restrict__ root_filler, const float* __restrict__ root_role,
    bf16* __restrict__ args, bf16* __restrict__ dpad,
    float* __restrict__ out, uint* __restrict__ flags)
{
    __shared__ char lds[73728];
    const int bid = blockIdx.x;
    const int tid = threadIdx.x;

    if (bid < 128) {
        // ---------------- producer ----------------
#pragma unroll
        for (int i = 0; i < 8; ++i)
            prep_dpad_chunk(bid*4096 + i*512 + tid, Dl, Dr, El, Er, dpad);
        __threadfence();
        __syncthreads();
        if (tid == 0)
            __hip_atomic_fetch_add(&flags[0], 1u, __ATOMIC_RELEASE,
                                   __HIP_MEMORY_SCOPE_AGENT);
        const int h = tid >> 8, t = tid & 255;
        for (int g = 0; g < 16; ++g) {
            prep_args_row(g*256 + bid*2 + h, t, x, w0, w1, w2, w3, args);
            __threadfence();
            __syncthreads();
            if (tid == 0)
                __hip_atomic_fetch_add(&flags[1+g], 1u, __ATOMIC_RELEASE,
                                       __HIP_MEMORY_SCOPE_AGENT);
        }
        if (bid == 0 && tid < 256) prep_stats(tid, w0, w1, w2, w3, out);
    }

    // ---------------- consumer (everyone) ----------------
    if (tid == 0) {
        while (__hip_atomic_load(&flags[0], __ATOMIC_RELAXED,
                                 __HIP_MEMORY_SCOPE_AGENT) < 128u)
            __builtin_amdgcn_s_sleep(64);
        (void)__hip_atomic_load(&flags[0], __ATOMIC_ACQUIRE,
                                __HIP_MEMORY_SCOPE_AGENT);   // one inv
    }
    __syncthreads();

    int got = -1;
    for (;;) {
        if (tid == 0) {
            uint tk = __hip_atomic_fetch_add(&flags[17], 1u, __ATOMIC_RELAXED,
                                             __HIP_MEMORY_SCOPE_AGENT);
            *(volatile uint*)lds = tk;
        }
        __syncthreads();
        const uint tk = *(volatile uint*)lds;
        __syncthreads();
        if (tk >= 384u) break;

        const int g   = tk / 24;
        const int r   = tk % 24;               // cons first (longest)
        const int job = (r < 8) ? 2 : (r < 16) ? 0 : 1;
        const int mt  = g*2 + ((r >> 2) & 1);
        const int nt  = r & 3;

        if (g > got) {
            if (tid == 0) {
                while (__hip_atomic_load(&flags[1+g], __ATOMIC_RELAXED,
                                         __HIP_MEMORY_SCOPE_AGENT) < 128u)
                    __builtin_amdgcn_s_sleep(64);
                (void)__hip_atomic_load(&flags[1+g], __ATOMIC_ACQUIRE,
                                        __HIP_MEMORY_SCOPE_AGENT);
            }
            got = g;
        }
        __syncthreads();

        if (job == 2)
            gemm_t<64, true >(args + 8388608, dpad + 2097152,
                root_filler, root_role, out + 2*(size_t)BFR, lds, mt, nt);
        else if (job == 0)
            gemm_t<32, false>(args, dpad,
                root_filler, root_role, out, lds, mt, nt);
        else
            gemm_t<32, false>(args + 4194304, dpad + 1048576,
                root_filler, root_role, out + (size_t)BFR, lds, mt, nt);
        __syncthreads();
    }
}

// ---------------------------------------------------------------------------
extern "C" void kernel_launch(void* const* d_in, const int* in_sizes, int n_in,
                              void* d_out, int out_size, void* d_ws, size_t ws_size,
                              hipStream_t stream)
{
    const float* x           = (const float*)d_in[0];
    const float* car_w       = (const float*)d_in[1];
    const float* cdr_w       = (const float*)d_in[2];
    const float* cons1_w     = (const float*)d_in[3];
    const float* cons2_w     = (const float*)d_in[4];
    const float* root_filler = (const float*)d_in[5];
    const float* Dl          = (const float*)d_in[6];
    const float* Dr          = (const float*)d_in[7];
    const float* El          = (const float*)d_in[8];
    const float* Er          = (const float*)d_in[9];
    const float* root_role   = (const float*)d_in[10];
    float* out = (float*)d_out;

    bf16* args  = (bf16*)d_ws;                            // 33.5 MB
    bf16* dpad  = args + 16777216;                        //  8.4 MB
    uint* flags = (uint*)((char*)d_ws + 41943040);        // 18 uints

    hipMemsetAsync(flags, 0, 18 * sizeof(uint), stream);
    k_all<<<dim3(384), dim3(512), 0, stream>>>(
        x, car_w, cdr_w, cons1_w, cons2_w, Dl, Dr, El, Er,
        root_filler, root_role, args, dpad, out, flags);
}

// Round 12
// 109.067 us; speedup vs baseline: 8.8827x; 8.8827x over previous
//
#include <hip/hip_runtime.h>
#include <hip/hip_bf16.h>
#include <stdint.h>

#define Rdim 1023
#define BFR  4190208           // 64*64*1023

typedef __bf16 bf16;
typedef __bf16 bf16x8 __attribute__((ext_vector_type(8)));
typedef __bf16 bf16x2 __attribute__((ext_vector_type(2)));
typedef float  f32x4  __attribute__((ext_vector_type(4)));
typedef float  f32x4u __attribute__((ext_vector_type(4), aligned(4)));

__device__ __forceinline__ void async16(const void* g, void* l) {
    __builtin_amdgcn_global_load_lds(
        (const __attribute__((address_space(1))) void*)g,
        (__attribute__((address_space(3))) void*)l, 16, 0, 0);
}

#define BAR()  do { __builtin_amdgcn_s_barrier(); __builtin_amdgcn_sched_barrier(0); } while(0)

// ---------------------------------------------------------------------------
// Prep, LDS-DMA version. Blocks [0,2048): dpad (r10 body). Block 2048: stats.
// Blocks [2049,2561): args — 512 blocks x 16 steps; per step one half-row
// (m = h>>1, half = h&1) is DMA'd into a 32 KB LDS buffer (16 l-slices x
// 2 KB) with 8 async16/thread (no dest VGPRs -> 64 KB/CU in flight vs the
// ~9 KB BW*latency product), double-buffered with counted vmcnt(8) and raw
// s_barriers. Swizzle identical to r10: chunk c of row m stored at
// (c&~3)|((c&3)^((m>>1)&3)) — GEMM unchanged.
// ---------------------------------------------------------------------------
__global__ __launch_bounds__(256) void k_prep(
    const float* __restrict__ x,
    const float* __restrict__ w0, const float* __restrict__ w1,
    const float* __restrict__ w2, const float* __restrict__ w3,
    const float* __restrict__ Dl, const float* __restrict__ Dr,
    const float* __restrict__ El, const float* __restrict__ Er,
    bf16* __restrict__ args, bf16* __restrict__ dpad,
    float* __restrict__ out)
{
    __shared__ char plds[65536];
    const int blk = blockIdx.x;
    const int t   = threadIdx.x;

    if (blk < 2048) {
        // ---- dpad: one 16B chunk per thread (r10 verbatim) ----
        const int id = blk*256 + t;
        const float* src; int n, c, K; size_t base;
        if (id < 262144) {
            const int m2  = id >> 17;
            src = m2 ? Dr : Dl;
            const int rem = id & 131071;
            n = rem >> 7; c = rem & 127; K = 1024;
            base = m2 ? 1048576u : 0u;
        } else {
            const int rem = id - 262144;
            n = rem >> 8; c = rem & 255; K = 2048;
            base = 2097152u;
            src = (c < 128) ? El : Er;
        }
        const int cl = c & 127;
        float v[8] = {};
        if (n < Rdim) {
            const float* sp = src + (size_t)n*Rdim + cl*8;
            if (cl < 127) {
                f32x4u u0 = *(const f32x4u*)sp;
                f32x4u u1 = *(const f32x4u*)(sp + 4);
#pragma unroll
                for (int j = 0; j < 4; ++j) { v[j] = u0[j]; v[4+j] = u1[j]; }
            } else {
                f32x4u u0 = *(const f32x4u*)sp;
#pragma unroll
                for (int j = 0; j < 4; ++j) v[j] = u0[j];
                v[4] = sp[4]; v[5] = sp[5]; v[6] = sp[6];
            }
        }
        const int swc = (c & ~3) | ((c & 3) ^ ((n >> 1) & 3));
        bf16x8 s;
#pragma unroll
        for (int j = 0; j < 8; ++j) s[j] = (bf16)v[j];
        *(bf16x8*)(dpad + base + (size_t)n*K + swc*8) = s;
    } else if (blk == 2048) {
        // ---- stats ----
        const int k = t >> 6, b2 = t & 63;
        const float* w = (k==0) ? w0 : (k==1) ? w1 : (k==2) ? w2 : w3;
        float s = 0.f, mx = -1e30f;
#pragma unroll
        for (int l = 0; l < 16; ++l) {
            float p = w[b2*16 + l];
            s += p * logf(p + 1e-12f);
            mx = fmaxf(mx, p);
        }
        out[3*(size_t)BFR +       k*64 + b2] = -s / logf(16.f);
        out[3*(size_t)BFR + 256 + k*64 + b2] = mx;
    } else {
        // ---- args via LDS DMA ----
        const int b512 = blk - 2049;                   // 0..511
        const char* xB    = (const char*)x;
        const char* xlast = xB + (size_t)67043328*4 - 16;   // clamp target
        const int wv = t >> 6;
        const int la16 = (t & 63) * 16;

#define PISSUE(STEP, BUF) do {                                                \
    const int h_ = (STEP)*512 + b512;                                         \
    const int m_ = h_ >> 1, half_ = h_ & 1;                                   \
    const size_t rowB_ = (size_t)((m_>>6)*1024 + (m_&63)) * 4092;             \
    _Pragma("unroll") for (int j = 0; j < 8; ++j) {                           \
        const int q_ = wv*8 + j, l_ = q_ >> 1, sub_ = q_ & 1;                 \
        const char* s_ = xB + rowB_ + (size_t)l_*261888                       \
                            + half_*2048 + sub_*1024 + la16;                  \
        if (s_ > xlast) s_ = xlast;                                           \
        async16(s_, plds + (BUF)*32768 + q_*1024);                            \
    }                                                                         \
} while(0)

        PISSUE(0, 0);
        for (int s = 0; s < 16; ++s) {
            if (s < 15) { PISSUE(s+1, (s+1)&1);
                          asm volatile("s_waitcnt vmcnt(8)" ::: "memory"); }
            else        { asm volatile("s_waitcnt vmcnt(0)" ::: "memory"); }
            BAR();
            const int h = s*512 + b512, m = h >> 1, half = h & 1;
            const int bq = m >> 6;
            float a0[2] = {}, a1[2] = {}, a2[2] = {}, a3[2] = {};
            const char* bb = plds + (s & 1)*32768;
#pragma unroll
            for (int l = 0; l < 16; ++l) {
                const float2 v = *(const float2*)(bb + l*2048 + t*8);
                const float u0 = w0[bq*16 + l], u1 = w1[bq*16 + l];
                const float u2 = w2[bq*16 + l], u3 = w3[bq*16 + l];
                a0[0] += u0*v.x; a0[1] += u0*v.y;
                a1[0] += u1*v.x; a1[1] += u1*v.y;
                a2[0] += u2*v.x; a2[1] += u2*v.y;
                a3[0] += u3*v.x; a3[1] += u3*v.y;
            }
            if (half == 1 && t == 255) {               // r = 1023 pad column
                a0[1] = a1[1] = a2[1] = a3[1] = 0.f;
            }
            const int r0  = half*512 + t*2;
            const int c   = r0 >> 3;
            const int S2  = (m >> 1) & 3;
            const int off = (((c & ~3) | ((c & 3) ^ S2)) << 3) + (r0 & 7);
            bf16x2 s0, s1, s2, s3;
            s0[0] = (bf16)a0[0]; s0[1] = (bf16)a0[1];
            s1[0] = (bf16)a1[0]; s1[1] = (bf16)a1[1];
            s2[0] = (bf16)a2[0]; s2[1] = (bf16)a2[1];
            s3[0] = (bf16)a3[0]; s3[1] = (bf16)a3[1];
            *(bf16x2*)(args +            (size_t)m*1024 + off) = s0;   // car
            *(bf16x2*)(args + 4194304 +  (size_t)m*1024 + off) = s1;   // cdr
            bf16* c12 = args + 8388608 + (size_t)m*2048;
            *(bf16x2*)(c12 + off)        = s2;                         // c1
            *(bf16x2*)(c12 + 1024 + off) = s3;                         // c2
            BAR();
        }
#undef PISSUE

        // tail patch: the clamped final chunk corrupted (m=4095, l=15,
        // r=1020..1022) contributions — recompute those 3 outputs exactly.
        if (b512 == 511 && t < 3) {
            asm volatile("s_waitcnt vmcnt(0)" ::: "memory");
            const int r = 1020 + t;
            float s0 = 0.f, s1 = 0.f, s2 = 0.f, s3 = 0.f;
#pragma unroll
            for (int l = 0; l < 16; ++l) {
                const float xv = x[(size_t)(63*1024 + 63)*1023
                                   + (size_t)l*65472 + r];
                s0 += w0[63*16 + l]*xv; s1 += w1[63*16 + l]*xv;
                s2 += w2[63*16 + l]*xv; s3 += w3[63*16 + l]*xv;
            }
            const int off = (124 << 3) + (r & 7);      // c=127, S2=3 -> cw=124
            args[(size_t)4095*1024 + off]           = (bf16)s0;
            args[4194304 + (size_t)4095*1024 + off] = (bf16)s1;
            bf16* c12 = args + 8388608 + (size_t)4095*2048;
            c12[off]        = (bf16)s2;
            c12[1024 + off] = (bf16)s3;
        }
    }
}

// ---------------------------------------------------------------------------
// GEMM — r10 verbatim (107.1 µs baseline): BK=32, triple-buffered,
// 1 barrier/kt, counted vmcnt; car/cdr BM=256, cons BM=128; 256 blocks,
// each exactly one work unit; 96 KiB LDS.
// ---------------------------------------------------------------------------
template<int BM, int NKT, int VM, bool CONS>
__device__ __forceinline__ void gemm_t(
    const bf16* __restrict__ Ab, const bf16* __restrict__ Bb,
    const float* __restrict__ rf, const float* __restrict__ rr,
    float* __restrict__ outp, char* lds, int mt, int nt)
{
    constexpr int AstB = CONS ? 4096 : 2048;
    constexpr int MI   = BM / 32;
    constexpr int ABUF = BM * 64;

    const int tid  = threadIdx.x;
    const int wave = tid >> 6, lane = tid & 63;
    const int wm   = wave >> 2, wn = wave & 3;
    const int lr   = lane & 15, lk = lane >> 4;
    const int cc16 = (lk ^ ((lr >> 1) & 3)) << 4;

    const char* AgT = (const char*)Ab + (size_t)(mt*BM  + (tid>>2))*AstB + (tid&3)*16;
    const char* BgT = (const char*)Bb + (size_t)(nt*256 + (tid>>2))*AstB + (tid&3)*16;

    f32x4 acc[MI][4] = {};
    bf16x8 af[MI], bfr[4];

#define STG(bufidx, kt) do {                                                  \
    char* _a = lds + (bufidx)*ABUF + wave*1024;                               \
    char* _b = lds + 49152 + (bufidx)*16384 + wave*1024;                      \
    const size_t _ko = (size_t)(kt)*64;                                       \
    _Pragma("unroll") for (int i = 0; i < BM/128; ++i)                        \
        async16(AgT + (size_t)(i*128)*AstB + _ko, _a + i*8192);               \
    _Pragma("unroll") for (int i = 0; i < 2; ++i)                             \
        async16(BgT + (size_t)(i*128)*AstB + _ko, _b + i*8192);               \
} while(0)

    STG(0, 0); STG(1, 1);
    asm volatile("s_waitcnt vmcnt(%0)" :: "n"(VM) : "memory");
    BAR();

    int cb = 0;
    for (int kt = 0; kt < NKT; ++kt) {
        char* cA = lds + cb*ABUF;
        char* cB = lds + 49152 + cb*16384;
        int sb = cb + 2; if (sb >= 3) sb -= 3;
        const bool st = (kt + 2 < NKT);
#pragma unroll
        for (int mi = 0; mi < MI; ++mi)
            af[mi] = *(const bf16x8*)(cA + (wm*(BM/2) + mi*16 + lr)*64 + cc16);
#pragma unroll
        for (int j = 0; j < 4; ++j)
            bfr[j] = *(const bf16x8*)(cB + (wn*64 + j*16 + lr)*64 + cc16);
        if (st) STG(sb, kt+2);
        __builtin_amdgcn_s_setprio(1);
#pragma unroll
        for (int mi = 0; mi < MI; ++mi)
#pragma unroll
        for (int j = 0; j < 4; ++j)
            acc[mi][j] = __builtin_amdgcn_mfma_f32_16x16x32_bf16(
                af[mi], bfr[j], acc[mi][j], 0, 0, 0);
        __builtin_amdgcn_s_setprio(0);
        if (st)                { asm volatile("s_waitcnt vmcnt(%0)" :: "n"(VM) : "memory"); }
        else if (kt == NKT-2)  { asm volatile("s_waitcnt vmcnt(0)" ::: "memory"); }
        BAR();
        cb = cb + 1; if (cb == 3) cb = 0;
    }
#undef STG

#pragma unroll
    for (int mi = 0; mi < MI; ++mi) {
        const int gm0 = mt*BM + wm*(BM/2) + mi*16 + lk*4;
#pragma unroll
        for (int j = 0; j < 4; ++j) {
            const int gn = nt*256 + wn*64 + j*16 + lr;
            if (gn < Rdim) {
                const float rv = CONS ? rr[gn] : 0.f;
#pragma unroll
                for (int q = 0; q < 4; ++q) {
                    float v = acc[mi][j][q];
                    if (CONS) v += rf[gm0 + q] * rv;
                    outp[(size_t)(gm0 + q)*Rdim + gn] = v;
                }
            }
        }
    }
}

__global__ __launch_bounds__(512, 1) void k_gemm(
    const bf16* __restrict__ args, const bf16* __restrict__ dpad,
    const float* __restrict__ root_filler, const float* __restrict__ root_role,
    float* __restrict__ out)
{
    __shared__ char lds[98304];
    const int bid = blockIdx.x;
    const int xcd = bid & 7, idx = bid >> 3;

    if (idx < 16) {
        const int tile = xcd*16 + idx;
        gemm_t<128, 64, 3, true >(args + 8388608, dpad + 2097152,
            root_filler, root_role, out + 2*(size_t)BFR, lds, tile >> 2, tile & 3);
    } else if (idx < 24) {
        const int tile = xcd*8 + idx - 16;
        gemm_t<256, 32, 4, false>(args, dpad,
            root_filler, root_role, out, lds, tile >> 2, tile & 3);
    } else {
        const int tile = xcd*8 + idx - 24;
        gemm_t<256, 32, 4, false>(args + 4194304, dpad + 1048576,
            root_filler, root_role, out + (size_t)BFR, lds, tile >> 2, tile & 3);
    }
}

// ---------------------------------------------------------------------------
extern "C" void kernel_launch(void* const* d_in, const int* in_sizes, int n_in,
                              void* d_out, int out_size, void* d_ws, size_t ws_size,
                              hipStream_t stream)
{
    const float* x           = (const float*)d_in[0];
    const float* car_w       = (const float*)d_in[1];
    const float* cdr_w       = (const float*)d_in[2];
    const float* cons1_w     = (const float*)d_in[3];
    const float* cons2_w     = (const float*)d_in[4];
    const float* root_filler = (const float*)d_in[5];
    const float* Dl          = (const float*)d_in[6];
    const float* Dr          = (const float*)d_in[7];
    const float* El          = (const float*)d_in[8];
    const float* Er          = (const float*)d_in[9];
    const float* root_role   = (const float*)d_in[10];
    float* out = (float*)d_out;

    bf16* args = (bf16*)d_ws;                 // 33.5 MB
    bf16* dpad = args + 16777216;             //  8.4 MB

    k_prep<<<dim3(2561), dim3(256), 0, stream>>>(
        x, car_w, cdr_w, cons1_w, cons2_w, Dl, Dr, El, Er, args, dpad, out);
    k_gemm<<<dim3(256),  dim3(512), 0, stream>>>(
        args, dpad, root_filler, root_role, out);
}